// Round 1
// baseline (1516.896 us; speedup 1.0000x reference)
//
#include <hip/hip_runtime.h>
#include <hip/hip_bf16.h>
#include <math.h>

#define B 2048
#define D_IN 512
#define D_MODEL 1024
#define ED 2048
#define NSTATE 16
#define KCONV 4
#define DTDIM 64
#define FLAT_H (ED * NSTATE)                    /* 32768 */
#define ROW_STATE (FLAT_H + ED * (KCONV - 1))   /* 38912 */

__device__ __forceinline__ float sigmoidf_(float x) { return 1.f / (1.f + expf(-x)); }

// ---------------------------------------------------------------------------
// Tiled NT-GEMM: C[m,n] = sum_k A[m,k] * W[n,k]  (+ epilogue)
// A: M x K row-major (lda), W: N x K row-major (ldw), C: M x N row-major (ldc)
// MODE 0: plain store
// MODE 1: C = softplus(v + extra[n])          (bias + softplus)
// MODE 2: C = v + extra[m*ldc + n]            (residual add)
// 64x64 tile, BK=16, 256 threads, 4x4 per thread. K must be multiple of 16,
// M multiple of 64. N guarded.
// ---------------------------------------------------------------------------
template <int MODE>
__global__ __launch_bounds__(256) void gemm_nt(
    const float* __restrict__ A, const float* __restrict__ W,
    float* __restrict__ C, int M, int N, int K, int lda, int ldw, int ldc,
    const float* __restrict__ extra) {
  __shared__ float As[16][68];
  __shared__ float Ws[16][68];
  const int tid = threadIdx.x;
  const int tx = tid & 15;        // 0..15 -> n-subtile
  const int ty = tid >> 4;        // 0..15 -> m-subtile
  const int m0 = blockIdx.y * 64;
  const int n0 = blockIdx.x * 64;

  float acc[4][4] = {};

  const int lr = tid >> 4;  // 0..15 row group for loads
  const int lc = tid & 15;  // 0..15 k within tile

  for (int k0 = 0; k0 < K; k0 += 16) {
#pragma unroll
    for (int i = 0; i < 4; i++) {
      const int r = lr + i * 16;  // 0..63
      const int gk = k0 + lc;
      // A tile
      As[lc][r] = A[(size_t)(m0 + r) * lda + gk];
      // W tile (guard N)
      const int gn = n0 + r;
      Ws[lc][r] = (gn < N) ? W[(size_t)gn * ldw + gk] : 0.f;
    }
    __syncthreads();
#pragma unroll
    for (int k = 0; k < 16; k++) {
      float a[4], w[4];
#pragma unroll
      for (int i = 0; i < 4; i++) a[i] = As[k][ty * 4 + i];
#pragma unroll
      for (int j = 0; j < 4; j++) w[j] = Ws[k][tx * 4 + j];
#pragma unroll
      for (int i = 0; i < 4; i++)
#pragma unroll
        for (int j = 0; j < 4; j++) acc[i][j] += a[i] * w[j];
    }
    __syncthreads();
  }

#pragma unroll
  for (int i = 0; i < 4; i++) {
    const int gm = m0 + ty * 4 + i;
#pragma unroll
    for (int j = 0; j < 4; j++) {
      const int gn = n0 + tx * 4 + j;
      if (gn >= N) continue;
      float v = acc[i][j];
      if (MODE == 1) {
        v += extra[gn];
        v = (v > 20.f) ? v : log1pf(expf(v));
      } else if (MODE == 2) {
        v += extra[(size_t)gm * ldc + gn];
      }
      C[(size_t)gm * ldc + gn] = v;
    }
  }
}

// ---------------------------------------------------------------------------
// RMSNorm: one block per row of x (D_MODEL=1024), xn = x * rsqrt(mean(x^2)+eps) * w
// ---------------------------------------------------------------------------
__global__ __launch_bounds__(256) void rmsnorm_kernel(
    const float* __restrict__ x, const float* __restrict__ w,
    float* __restrict__ xn) {
  const int b = blockIdx.x;
  const float* xr = x + (size_t)b * D_MODEL;
  float ss = 0.f;
  for (int i = threadIdx.x; i < D_MODEL; i += 256) {
    float v = xr[i];
    ss += v * v;
  }
#pragma unroll
  for (int off = 32; off > 0; off >>= 1) ss += __shfl_down(ss, off, 64);
  __shared__ float red[4];
  if ((threadIdx.x & 63) == 0) red[threadIdx.x >> 6] = ss;
  __syncthreads();
  const float tot = red[0] + red[1] + red[2] + red[3];
  const float scale = rsqrtf(tot * (1.f / (float)D_MODEL) + 1e-5f);
  float* xnr = xn + (size_t)b * D_MODEL;
  for (int i = threadIdx.x; i < D_MODEL; i += 256) xnr[i] = xr[i] * scale * w[i];
}

// ---------------------------------------------------------------------------
// Conv window + SiLU; also writes inputs_new (shifted window) into flat_new.
// One thread per (b, e).
// ---------------------------------------------------------------------------
__global__ __launch_bounds__(256) void conv_silu_kernel(
    const float* __restrict__ flat_state, const float* __restrict__ xz,
    const float* __restrict__ conv_w, const float* __restrict__ conv_b,
    float* __restrict__ xs, float* __restrict__ outFlat) {
  const int id = blockIdx.x * 256 + threadIdx.x;
  const int b = id >> 11;       // /ED
  const int e = id & (ED - 1);  // %ED
  const float* inp = flat_state + (size_t)b * ROW_STATE + FLAT_H + e * 3;
  const float i0 = inp[0], i1 = inp[1], i2 = inp[2];
  const float x1 = xz[(size_t)b * (2 * ED) + e];
  const float* cw = conv_w + e * 4;
  const float xc = i0 * cw[0] + i1 * cw[1] + i2 * cw[2] + x1 * cw[3] + conv_b[e];
  xs[(size_t)b * ED + e] = xc * sigmoidf_(xc);
  float* on = outFlat + (size_t)b * ROW_STATE + FLAT_H + e * 3;
  on[0] = i1;
  on[1] = i2;
  on[2] = x1;
}

// ---------------------------------------------------------------------------
// SSM state update: h_new = exp(delta*A)*h + delta*B*xs ; y = <h_new, C> + D*xs
// yz = y * silu(z). h_new written directly to flat_new. One thread per (b, e).
// ---------------------------------------------------------------------------
__global__ __launch_bounds__(256) void state_kernel(
    const float* __restrict__ flat_state, const float* __restrict__ xz,
    const float* __restrict__ xs, const float* __restrict__ dbc,
    const float* __restrict__ delta, const float* __restrict__ A_log,
    const float* __restrict__ D_param, float* __restrict__ outFlat,
    float* __restrict__ yz) {
  const int id = blockIdx.x * 256 + threadIdx.x;
  const int b = id >> 11;
  const int e = id & (ED - 1);
  const float d = delta[(size_t)b * ED + e];
  const float xsv = xs[(size_t)b * ED + e];
  const float* hb = flat_state + (size_t)b * ROW_STATE + e * NSTATE;
  float* ho = outFlat + (size_t)b * ROW_STATE + e * NSTATE;
  const float* dbcb = dbc + (size_t)b * 96;
  const float* al = A_log + e * NSTATE;
  float y = 0.f;
#pragma unroll
  for (int n = 0; n < NSTATE; n++) {
    const float Aen = -expf(al[n]);
    const float dA = expf(d * Aen);
    const float hn = dA * hb[n] + d * dbcb[DTDIM + n] * xsv;
    ho[n] = hn;
    y += hn * dbcb[DTDIM + NSTATE + n];
  }
  y += D_param[e] * xsv;
  const float z = xz[(size_t)b * (2 * ED) + ED + e];
  yz[(size_t)b * ED + e] = y * (z * sigmoidf_(z));
}

extern "C" void kernel_launch(void* const* d_in, const int* in_sizes, int n_in,
                              void* d_out, int out_size, void* d_ws, size_t ws_size,
                              hipStream_t stream) {
  const float* x_t       = (const float*)d_in[0];
  const float* flat_state= (const float*)d_in[1];
  const float* W_in_cell = (const float*)d_in[2];
  const float* norm_w    = (const float*)d_in[3];
  const float* W_in      = (const float*)d_in[4];
  const float* conv_w    = (const float*)d_in[5];
  const float* conv_b    = (const float*)d_in[6];
  const float* W_xproj   = (const float*)d_in[7];
  const float* W_dt      = (const float*)d_in[8];
  const float* b_dt      = (const float*)d_in[9];
  const float* A_log     = (const float*)d_in[10];
  const float* D_param   = (const float*)d_in[11];
  const float* W_out     = (const float*)d_in[12];

  float* y_t_out = (float*)d_out;                      // B x D_MODEL
  float* outFlat = (float*)d_out + (size_t)B * D_MODEL; // B x ROW_STATE

  float* ws = (float*)d_ws;
  float* x     = ws;                                   // B x D_MODEL (residual)
  float* xn    = x + (size_t)B * D_MODEL;              // B x D_MODEL
  float* xz    = xn + (size_t)B * D_MODEL;             // B x 2ED
  float* xs    = xz + (size_t)B * 2 * ED;              // B x ED
  float* dbc   = xs + (size_t)B * ED;                  // B x 96
  float* delta = dbc + (size_t)B * 96;                 // B x ED
  float* yz    = delta + (size_t)B * ED;               // B x ED

  dim3 blk(256);

  // 1) x = x_t @ W_in_cell^T
  gemm_nt<0><<<dim3(D_MODEL / 64, B / 64), blk, 0, stream>>>(
      x_t, W_in_cell, x, B, D_MODEL, D_IN, D_IN, D_IN, D_MODEL, nullptr);
  // 2) xn = rmsnorm(x) * norm_w
  rmsnorm_kernel<<<dim3(B), blk, 0, stream>>>(x, norm_w, xn);
  // 3) xz = xn @ W_in^T
  gemm_nt<0><<<dim3(2 * ED / 64, B / 64), blk, 0, stream>>>(
      xn, W_in, xz, B, 2 * ED, D_MODEL, D_MODEL, D_MODEL, 2 * ED, nullptr);
  // 4) conv + silu -> xs ; inputs_new -> flat_new
  conv_silu_kernel<<<dim3((B * ED) / 256), blk, 0, stream>>>(
      flat_state, xz, conv_w, conv_b, xs, outFlat);
  // 5) dbc = xs @ W_xproj^T
  gemm_nt<0><<<dim3(2, B / 64), blk, 0, stream>>>(
      xs, W_xproj, dbc, B, 96, ED, ED, ED, 96, nullptr);
  // 6) delta = softplus(dbc[:, :64] @ W_dt^T + b_dt)
  gemm_nt<1><<<dim3(ED / 64, B / 64), blk, 0, stream>>>(
      dbc, W_dt, delta, B, ED, DTDIM, 96, DTDIM, ED, b_dt);
  // 7) state update -> h_new (flat_new), yz
  state_kernel<<<dim3((B * ED) / 256), blk, 0, stream>>>(
      flat_state, xz, xs, dbc, delta, A_log, D_param, outFlat, yz);
  // 8) y_t = yz @ W_out^T + residual
  gemm_nt<2><<<dim3(D_MODEL / 64, B / 64), blk, 0, stream>>>(
      yz, W_out, y_t_out, B, D_MODEL, ED, ED, ED, D_MODEL, x);
}